// Round 2
// baseline (536.619 us; speedup 1.0000x reference)
//
#include <hip/hip_runtime.h>

typedef unsigned short u16;
typedef __bf16 bf16x8 __attribute__((ext_vector_type(8)));
typedef float f32x4 __attribute__((ext_vector_type(4)));

// ---------- helpers ----------

__device__ __forceinline__ u16 f2bf(float f) {
  unsigned u = __float_as_uint(f);
  u += 0x7fffu + ((u >> 16) & 1u);   // RNE
  return (u16)(u >> 16);
}

__device__ __forceinline__ ushort4 f2bf4(float4 v) {
  return make_ushort4(f2bf(v.x), f2bf(v.y), f2bf(v.z), f2bf(v.w));
}

__device__ __forceinline__ void load_lds16(const void* g, void* l) {
  __builtin_amdgcn_global_load_lds(
      (const __attribute__((address_space(1))) void*)g,
      (__attribute__((address_space(3))) void*)l, 16, 0, 0);
}

__device__ __forceinline__ void conv_seg(const float* __restrict__ s,
                                         u16* __restrict__ d, int n4,
                                         int g, int stride) {
  const float4* s4 = (const float4*)s;
  ushort4* d4 = (ushort4*)d;
  for (int i = g; i < n4; i += stride) {
    float4 v = s4[i];
    d4[i] = make_ushort4(f2bf(v.x), f2bf(v.y), f2bf(v.z), f2bf(v.w));
  }
}

// ---------- prep: fp32->bf16 converts, bias concat, rope table ----------

__global__ __launch_bounds__(256) void prep(
    const float* __restrict__ hid, const float* __restrict__ wqa,
    const float* __restrict__ wkva, const float* __restrict__ wqb,
    const float* __restrict__ wkvb, const float* __restrict__ bqa,
    const float* __restrict__ bkva, u16* __restrict__ hid_b,
    u16* __restrict__ wab_b, u16* __restrict__ wqb_b,
    u16* __restrict__ wkvb_b, float* __restrict__ bias_ab,
    float* __restrict__ cosT, float* __restrict__ sinT) {
  int g = blockIdx.x * 256 + threadIdx.x;
  int stride = gridDim.x * 256;
  conv_seg(hid, hid_b, 4194304, g, stride);
  conv_seg(wqa, wab_b, 393216, g, stride);                 // rows 0..767
  conv_seg(wkva, wab_b + 768 * 2048, 294912, g, stride);   // rows 768..1343
  conv_seg(wqb, wqb_b, 589824, g, stride);
  conv_seg(wkvb, wkvb_b, 524288, g, stride);
  if (g < 1344) bias_ab[g] = (g < 768) ? bqa[g] : bkva[g - 768];
  for (int idx = g; idx < 131072; idx += stride) {
    int s = idx >> 5, i = idx & 31;
    float inv = powf(10000.f, -(float)i / 32.f);
    float f = (float)s * inv;
    float sv, cv;
    sincosf(f, &sv, &cv);
    cosT[idx] = cv;
    sinT[idx] = sv;
  }
}

// ---------- GEMM: C = A(Mx K bf16) @ B^T(N x K bf16) + bias ----------
// WHICH=0: merged q_c|kv_c -> qkvc fp32 (N=1344, stride 1344, K=2048)
// WHICH=1: merged B-gemms -> out; y<24 = Q (K=768, fused RoPE),
//          else KV (K=512)
// Both launches use gridDim.x == 64 (x-tile over M=8192).
// launch_bounds (256,2): (256,3) caps VGPR ~170 -> K-loop spills, +12% dur
// (measured R1 535us vs 475us). Do not raise min-waves without checking
// kernel-resource-usage.

template <int WHICH>
__global__ __launch_bounds__(256, 2) void gemm_k(
    const u16* __restrict__ A0, const u16* __restrict__ B0,
    const float* __restrict__ bias0, float* __restrict__ C0,
    const u16* __restrict__ qA, const u16* __restrict__ qB,
    const float* __restrict__ qb, const u16* __restrict__ kA,
    const u16* __restrict__ kB, const float* __restrict__ kb,
    float* __restrict__ out, const float* __restrict__ cosT,
    const float* __restrict__ sinT) {
  __shared__ __align__(16) u16 smem[2 * 128 * 64];
  u16* sA = smem;
  u16* sB = smem + 128 * 64;
  const int tid = threadIdx.x;
  const int lane = tid & 63;
  const int wave = tid >> 6;
  const int wm = (wave >> 1) * 64;
  const int wn = (wave & 1) * 64;
  const int lane15 = lane & 15;
  const int quad = lane >> 4;

  // XCD-aware bijective swizzle (T1). nwg%8==0 for both grids (704, 3584).
  const int nwg = gridDim.x * gridDim.y;          // gridDim.x == 64
  const int fid = blockIdx.y * 64 + blockIdx.x;
  const int nfid = (fid & 7) * (nwg >> 3) + (fid >> 3);
  const int bx = nfid & 63;
  const int by = nfid >> 6;

  const int mTile = bx * 128;

  const u16* A;
  const u16* B;
  const float* bias;
  int K, nTile, mode;
  if (WHICH == 0) {
    A = A0; B = B0; bias = bias0; K = 2048; nTile = by * 128; mode = 0;
  } else if (by < 24) {
    A = qA; B = qB; bias = qb; K = 768; nTile = by * 128; mode = 1;
  } else {
    A = kA; B = kB; bias = kb; K = 512; nTile = (by - 24) * 128;
    mode = 2;
  }

  f32x4 acc[4][4] = {};

  const int nStages = K >> 6;
  for (int ks = 0; ks < nStages; ++ks) {
    const int k0 = ks << 6;
    if (ks) __syncthreads();
#pragma unroll
    for (int i = 0; i < 4; ++i) {
      int nu = i * 256 + tid;
      int rr = nu >> 3, u = nu & 7;
      int ul = u ^ (rr & 7);
      load_lds16(A + (size_t)(mTile + rr) * K + (k0 + ul * 8),
                 &sA[(i * 256 + (wave << 6)) * 8]);
    }
#pragma unroll
    for (int i = 0; i < 4; ++i) {
      int nu = i * 256 + tid;
      int rr = nu >> 3, u = nu & 7;
      int ul = u ^ (rr & 7);
      int brow = nTile + rr;
      if (WHICH == 0 && brow >= 1344) brow = 1343;
      load_lds16(B + (size_t)brow * K + (k0 + ul * 8),
                 &sB[(i * 256 + (wave << 6)) * 8]);
    }
    __syncthreads();
#pragma unroll
    for (int kk = 0; kk < 2; ++kk) {
      bf16x8 af[4], bfv[4];
#pragma unroll
      for (int mi = 0; mi < 4; ++mi) {
        int r = wm + mi * 16 + lane15;
        int u = (kk * 4 + quad) ^ (r & 7);
        af[mi] = *(const bf16x8*)&sA[(r * 8 + u) * 8];
      }
#pragma unroll
      for (int ni = 0; ni < 4; ++ni) {
        int r = wn + ni * 16 + lane15;
        int u = (kk * 4 + quad) ^ (r & 7);
        bfv[ni] = *(const bf16x8*)&sB[(r * 8 + u) * 8];
      }
#pragma unroll
      for (int mi = 0; mi < 4; ++mi)
#pragma unroll
        for (int ni = 0; ni < 4; ++ni)
          acc[mi][ni] = __builtin_amdgcn_mfma_f32_16x16x32_bf16(
              af[mi], bfv[ni], acc[mi][ni], 0, 0, 0);
    }
  }

  // ---------- epilogue: bias (+rope), LDS transpose, float4 stores ----------
  const int colW = nTile + wn;
  float bv[4];
#pragma unroll
  for (int ni = 0; ni < 4; ++ni) {
    int col = colW + ni * 16 + lane15;
    if (WHICH == 0)
      bv[ni] = (col < 1344) ? bias[col] : 0.f;
    else
      bv[ni] = bias[col];
  }

  int h = 0, ch0 = 0;
  if (mode == 1) {
    h = colW / 192;
    ch0 = colW % 192;
  } else if (mode == 2) {
    int jb = colW & 255;
    h = colW >> 8;
    ch0 = (jb < 128) ? (192 + jb) : (256 + jb);
  }
  const bool ropeTile = (mode == 1) && (ch0 == 128);

  __syncthreads();   // all waves done with K-loop LDS before reuse
  float* lw = (float*)smem + wave * (16 * 68);
  const int hi = lane15 >> 2, l3 = lane15 & 3;

#pragma unroll
  for (int mi = 0; mi < 4; ++mi) {
    f32x4 v[4];
#pragma unroll
    for (int ni = 0; ni < 4; ++ni)
#pragma unroll
      for (int rg = 0; rg < 4; ++rg) v[ni][rg] = acc[mi][ni][rg] + bv[ni];

    if (ropeTile) {
      int rowB = mTile + wm + mi * 16 + quad * 4;
#pragma unroll
      for (int rg = 0; rg < 4; ++rg) {
        int ss = (rowB + rg) & 4095;
#pragma unroll
        for (int ni = 0; ni < 2; ++ni) {
          int i = ni * 16 + lane15;
          float cv = cosT[ss * 32 + i], sv = sinT[ss * 32 + i];
          float x1 = v[ni][rg], x2 = v[ni + 2][rg];
          v[ni][rg] = x1 * cv - x2 * sv;
          v[ni + 2][rg] = x2 * cv + x1 * sv;
        }
      }
    }

    if (mi) asm volatile("s_waitcnt lgkmcnt(0)" ::: "memory");
#pragma unroll
    for (int ni = 0; ni < 4; ++ni) {
      int su = (4 * ni + hi) ^ quad;   // XOR low bits by writer quad (=rr>>2)
#pragma unroll
      for (int rg = 0; rg < 4; ++rg)
        lw[68 * (quad * 4 + rg) + 4 * su + l3] = v[ni][rg];
    }
    asm volatile("s_waitcnt lgkmcnt(0)" ::: "memory");
#pragma unroll
    for (int j = 0; j < 4; ++j) {
      int rr = 4 * j + quad;
      int su = lane15 ^ j;             // un-swizzle: writer quad for row rr is j
      float4 o = *(const float4*)&lw[68 * rr + 4 * su];
      int row = mTile + wm + mi * 16 + rr;
      if (mode == 0) {
        if (colW + 4 * lane15 < 1344)
          *(float4*)(C0 + (size_t)row * 1344 + colW + 4 * lane15) = o;
      } else {
        int bb = row >> 12, ss = row & 4095;
        size_t ob =
            ((size_t)((bb * 16 + h) * 4096 + ss)) * 512 + ch0 + 4 * lane15;
        *(float4*)(out + ob) = o;
      }
    }
  }
}

// ---------- LayerNorms + k_rot broadcast (vectorized, single reduction) ----------
// Row layout (1344 f32 = 336 float4): f4[0..191]=q_c, f4[192..319]=kv_c,
// f4[320..335]=k_rope. Thread t<256 loads f4[t]; t<80 also loads f4[256+t].

__global__ __launch_bounds__(256) void ln_rot(
    const float* __restrict__ qkvc, const float* __restrict__ g_q,
    const float* __restrict__ b_q, const float* __restrict__ g_kv,
    const float* __restrict__ b_kv, u16* __restrict__ q_ln,
    u16* __restrict__ kv_ln, const float* __restrict__ cosT,
    const float* __restrict__ sinT, float* __restrict__ out) {
  __shared__ float red[4][4];
  __shared__ __align__(16) float rot[64];
  const int tid = threadIdx.x;
  const int t = blockIdx.x;
  const int bb = t >> 12, ss = t & 4095;
  const float4* p4 = (const float4*)(qkvc + (size_t)t * 1344);

  float4 a = p4[tid];
  float4 b = make_float4(0.f, 0.f, 0.f, 0.f);
  if (tid < 80) b = p4[256 + tid];

  float sa = a.x + a.y + a.z + a.w;
  float sqa = a.x * a.x + a.y * a.y + a.z * a.z + a.w * a.w;
  float qs = 0.f, qq = 0.f, ks = 0.f, kq = 0.f;
  if (tid < 192) { qs = sa; qq = sqa; } else { ks = sa; kq = sqa; }
  if (tid < 64) {   // f4[256+tid] in kv range (256..319)
    ks += b.x + b.y + b.z + b.w;
    kq += b.x * b.x + b.y * b.y + b.z * b.z + b.w * b.w;
  }
#pragma unroll
  for (int off = 32; off > 0; off >>= 1) {
    qs += __shfl_down(qs, off, 64);
    qq += __shfl_down(qq, off, 64);
    ks += __shfl_down(ks, off, 64);
    kq += __shfl_down(kq, off, 64);
  }
  const int lane = tid & 63, wave = tid >> 6;
  if (lane == 0) {
    red[wave][0] = qs; red[wave][1] = qq;
    red[wave][2] = ks; red[wave][3] = kq;
  }
  __syncthreads();
  qs = red[0][0] + red[1][0] + red[2][0] + red[3][0];
  qq = red[0][1] + red[1][1] + red[2][1] + red[3][1];
  ks = red[0][2] + red[1][2] + red[2][2] + red[3][2];
  kq = red[0][3] + red[1][3] + red[2][3] + red[3][3];
  const float muq = qs * (1.f / 768.f);
  const float invq = rsqrtf(qq * (1.f / 768.f) - muq * muq + 1e-5f);
  const float muk = ks * (1.f / 512.f);
  const float invk = rsqrtf(kq * (1.f / 512.f) - muk * muk + 1e-5f);

  if (tid < 192) {
    float4 g = ((const float4*)g_q)[tid];
    float4 be = ((const float4*)b_q)[tid];
    float4 o = make_float4((a.x - muq) * invq * g.x + be.x,
                           (a.y - muq) * invq * g.y + be.y,
                           (a.z - muq) * invq * g.z + be.z,
                           (a.w - muq) * invq * g.w + be.w);
    ((ushort4*)(q_ln + (size_t)t * 768))[tid] = f2bf4(o);
  } else {
    int j = tid - 192;   // kv f4 col 0..63
    float4 g = ((const float4*)g_kv)[j];
    float4 be = ((const float4*)b_kv)[j];
    float4 o = make_float4((a.x - muk) * invk * g.x + be.x,
                           (a.y - muk) * invk * g.y + be.y,
                           (a.z - muk) * invk * g.z + be.z,
                           (a.w - muk) * invk * g.w + be.w);
    ((ushort4*)(kv_ln + (size_t)t * 512))[j] = f2bf4(o);
  }
  if (tid < 64) {
    int j = 64 + tid;    // kv f4 col 64..127
    float4 g = ((const float4*)g_kv)[j];
    float4 be = ((const float4*)b_kv)[j];
    float4 o = make_float4((b.x - muk) * invk * g.x + be.x,
                           (b.y - muk) * invk * g.y + be.y,
                           (b.z - muk) * invk * g.z + be.z,
                           (b.w - muk) * invk * g.w + be.w);
    ((ushort4*)(kv_ln + (size_t)t * 512))[j] = f2bf4(o);
  }
  // k_rot (64 ch), broadcast to 16 heads (out ch 320..383)
  if (tid < 32) {
    const float* p = qkvc + (size_t)t * 1344;
    float k1 = p[1280 + tid], k2 = p[1312 + tid];
    float cv = cosT[ss * 32 + tid], sv = sinT[ss * 32 + tid];
    rot[tid] = k1 * cv - k2 * sv;
    rot[tid + 32] = k2 * cv + k1 * sv;
  }
  __syncthreads();
  {
    int hh = tid >> 4, c4 = tid & 15;
    float4 o = ((const float4*)rot)[c4];
    *(float4*)(out + ((size_t)((bb * 16 + hh) * 4096 + ss)) * 512 + 320 +
               4 * c4) = o;
  }
}

// ---------- launch ----------

extern "C" void kernel_launch(void* const* d_in, const int* in_sizes, int n_in,
                              void* d_out, int out_size, void* d_ws,
                              size_t ws_size, hipStream_t stream) {
  const float* hidden = (const float*)d_in[0];
  const float* w_qa = (const float*)d_in[1];
  const float* b_qa = (const float*)d_in[2];
  const float* g_qa_ln = (const float*)d_in[3];
  const float* b_qa_ln = (const float*)d_in[4];
  const float* w_qb = (const float*)d_in[5];
  const float* b_qb = (const float*)d_in[6];
  const float* w_kva = (const float*)d_in[7];
  const float* b_kva = (const float*)d_in[8];
  const float* g_kva_ln = (const float*)d_in[9];
  const float* b_kva_ln = (const float*)d_in[10];
  const float* w_kvb = (const float*)d_in[11];
  const float* b_kvb = (const float*)d_in[12];
  float* out = (float*)d_out;

  char* ws = (char*)d_ws;
  u16* hid_bf = (u16*)ws;   ws += (size_t)16777216 * 2;
  u16* wab_bf = (u16*)ws;   ws += (size_t)1344 * 2048 * 2;
  u16* wqb_bf = (u16*)ws;   ws += (size_t)2359296 * 2;
  u16* wkvb_bf = (u16*)ws;  ws += (size_t)2097152 * 2;
  float* qkvc = (float*)ws; ws += (size_t)8192 * 1344 * 4;
  u16* q_ln = (u16*)ws;     ws += (size_t)6291456 * 2;
  u16* kv_ln = (u16*)ws;    ws += (size_t)4194304 * 2;
  float* cosT = (float*)ws; ws += (size_t)131072 * 4;
  float* sinT = (float*)ws; ws += (size_t)131072 * 4;
  float* bias_ab = (float*)ws; ws += (size_t)2048 * 4;

  prep<<<dim3(1024), dim3(256), 0, stream>>>(
      hidden, w_qa, w_kva, w_qb, w_kvb, b_qa, b_kva, hid_bf, wab_bf, wqb_bf,
      wkvb_bf, bias_ab, cosT, sinT);
  // merged A-GEMM: qkvc = hidden @ [w_qa;w_kva]^T + bias  (8192 x 1344, K=2048)
  gemm_k<0><<<dim3(64, 11), dim3(256), 0, stream>>>(
      hid_bf, wab_bf, bias_ab, qkvc, nullptr, nullptr, nullptr, nullptr,
      nullptr, nullptr, nullptr, cosT, sinT);
  ln_rot<<<dim3(8192), dim3(256), 0, stream>>>(qkvc, g_qa_ln, b_qa_ln,
                                               g_kva_ln, b_kva_ln, q_ln, kv_ln,
                                               cosT, sinT, out);
  // merged B-GEMMs: y<24 -> q (N=3072,K=768, RoPE fused); y>=24 -> kv (N=4096,K=512)
  gemm_k<1><<<dim3(64, 56), dim3(256), 0, stream>>>(
      nullptr, nullptr, nullptr, nullptr, q_ln, wqb_bf, b_qb, kv_ln, wkvb_bf,
      b_kvb, out, cosT, sinT);
}

// Round 3
// 471.614 us; speedup vs baseline: 1.1378x; 1.1378x over previous
//
#include <hip/hip_runtime.h>

typedef unsigned short u16;
typedef __bf16 bf16x8 __attribute__((ext_vector_type(8)));
typedef float f32x4 __attribute__((ext_vector_type(4)));

// ---------- helpers ----------

__device__ __forceinline__ u16 f2bf(float f) {
  unsigned u = __float_as_uint(f);
  u += 0x7fffu + ((u >> 16) & 1u);   // RNE
  return (u16)(u >> 16);
}

__device__ __forceinline__ ushort4 f2bf4(float4 v) {
  return make_ushort4(f2bf(v.x), f2bf(v.y), f2bf(v.z), f2bf(v.w));
}

__device__ __forceinline__ void load_lds16(const void* g, void* l) {
  __builtin_amdgcn_global_load_lds(
      (const __attribute__((address_space(1))) void*)g,
      (__attribute__((address_space(3))) void*)l, 16, 0, 0);
}

__device__ __forceinline__ void conv_seg(const float* __restrict__ s,
                                         u16* __restrict__ d, int n4,
                                         int g, int stride) {
  const float4* s4 = (const float4*)s;
  ushort4* d4 = (ushort4*)d;
  for (int i = g; i < n4; i += stride) {
    float4 v = s4[i];
    d4[i] = make_ushort4(f2bf(v.x), f2bf(v.y), f2bf(v.z), f2bf(v.w));
  }
}

// ---------- prep: fp32->bf16 converts, bias concat, rope table ----------

__global__ __launch_bounds__(256) void prep(
    const float* __restrict__ hid, const float* __restrict__ wqa,
    const float* __restrict__ wkva, const float* __restrict__ wqb,
    const float* __restrict__ wkvb, const float* __restrict__ bqa,
    const float* __restrict__ bkva, u16* __restrict__ hid_b,
    u16* __restrict__ wab_b, u16* __restrict__ wqb_b,
    u16* __restrict__ wkvb_b, float* __restrict__ bias_ab,
    float* __restrict__ cosT, float* __restrict__ sinT) {
  int g = blockIdx.x * 256 + threadIdx.x;
  int stride = gridDim.x * 256;
  conv_seg(hid, hid_b, 4194304, g, stride);
  conv_seg(wqa, wab_b, 393216, g, stride);                 // rows 0..767
  conv_seg(wkva, wab_b + 768 * 2048, 294912, g, stride);   // rows 768..1343
  conv_seg(wqb, wqb_b, 589824, g, stride);
  conv_seg(wkvb, wkvb_b, 524288, g, stride);
  if (g < 1344) bias_ab[g] = (g < 768) ? bqa[g] : bkva[g - 768];
  for (int idx = g; idx < 131072; idx += stride) {
    int s = idx >> 5, i = idx & 31;
    float inv = powf(10000.f, -(float)i / 32.f);
    float f = (float)s * inv;
    float sv, cv;
    sincosf(f, &sv, &cv);
    cosT[idx] = cv;
    sinT[idx] = sv;
  }
}

// ---------- GEMM: C = A(Mx K bf16) @ B^T(N x K bf16) + bias ----------
// WHICH=0: merged q_c|kv_c -> qkvc fp32 (N=1344, stride 1344, K=2048)
// WHICH=1: merged B-gemms -> out; blockIdx.y<24 = Q (K=768, fused RoPE),
//          else KV (K=512)
//
// NOTE (R1/R2 post-mortem): do NOT add a chunk-contiguous XCD swizzle here.
// Natural round-robin dispatch gives each XCD a fixed set of 8 bx A-tiles
// (1.6 MB, L2-resident across all by) — chunking per XCD streams all 64
// A-tiles through L2 with no reuse: measured +60us (475->536).
// Also: (256,3) launch bounds ties (256,2) — no spill headroom gained.

template <int WHICH>
__global__ __launch_bounds__(256, 2) void gemm_k(
    const u16* __restrict__ A0, const u16* __restrict__ B0,
    const float* __restrict__ bias0, float* __restrict__ C0,
    const u16* __restrict__ qA, const u16* __restrict__ qB,
    const float* __restrict__ qb, const u16* __restrict__ kA,
    const u16* __restrict__ kB, const float* __restrict__ kb,
    float* __restrict__ out, const float* __restrict__ cosT,
    const float* __restrict__ sinT) {
  __shared__ __align__(16) u16 smem[2 * 128 * 64];
  u16* sA = smem;
  u16* sB = smem + 128 * 64;
  const int tid = threadIdx.x;
  const int lane = tid & 63;
  const int wave = tid >> 6;
  const int wm = (wave >> 1) * 64;
  const int wn = (wave & 1) * 64;
  const int lane15 = lane & 15;
  const int quad = lane >> 4;
  const int mTile = blockIdx.x * 128;

  const u16* A;
  const u16* B;
  const float* bias;
  int K, nTile, mode;
  if (WHICH == 0) {
    A = A0; B = B0; bias = bias0; K = 2048; nTile = blockIdx.y * 128; mode = 0;
  } else if (blockIdx.y < 24) {
    A = qA; B = qB; bias = qb; K = 768; nTile = blockIdx.y * 128; mode = 1;
  } else {
    A = kA; B = kB; bias = kb; K = 512; nTile = (blockIdx.y - 24) * 128;
    mode = 2;
  }

  f32x4 acc[4][4] = {};

  const int nStages = K >> 6;
  for (int ks = 0; ks < nStages; ++ks) {
    const int k0 = ks << 6;
    if (ks) __syncthreads();
#pragma unroll
    for (int i = 0; i < 4; ++i) {
      int nu = i * 256 + tid;
      int rr = nu >> 3, u = nu & 7;
      int ul = u ^ (rr & 7);
      load_lds16(A + (size_t)(mTile + rr) * K + (k0 + ul * 8),
                 &sA[(i * 256 + (wave << 6)) * 8]);
    }
#pragma unroll
    for (int i = 0; i < 4; ++i) {
      int nu = i * 256 + tid;
      int rr = nu >> 3, u = nu & 7;
      int ul = u ^ (rr & 7);
      int brow = nTile + rr;
      if (WHICH == 0 && brow >= 1344) brow = 1343;
      load_lds16(B + (size_t)brow * K + (k0 + ul * 8),
                 &sB[(i * 256 + (wave << 6)) * 8]);
    }
    __syncthreads();
#pragma unroll
    for (int kk = 0; kk < 2; ++kk) {
      bf16x8 af[4], bfv[4];
#pragma unroll
      for (int mi = 0; mi < 4; ++mi) {
        int r = wm + mi * 16 + lane15;
        int u = (kk * 4 + quad) ^ (r & 7);
        af[mi] = *(const bf16x8*)&sA[(r * 8 + u) * 8];
      }
#pragma unroll
      for (int ni = 0; ni < 4; ++ni) {
        int r = wn + ni * 16 + lane15;
        int u = (kk * 4 + quad) ^ (r & 7);
        bfv[ni] = *(const bf16x8*)&sB[(r * 8 + u) * 8];
      }
#pragma unroll
      for (int mi = 0; mi < 4; ++mi)
#pragma unroll
        for (int ni = 0; ni < 4; ++ni)
          acc[mi][ni] = __builtin_amdgcn_mfma_f32_16x16x32_bf16(
              af[mi], bfv[ni], acc[mi][ni], 0, 0, 0);
    }
  }

  // ---------- epilogue: bias (+rope), LDS transpose, float4 stores ----------
  const int colW = nTile + wn;
  float bv[4];
#pragma unroll
  for (int ni = 0; ni < 4; ++ni) {
    int col = colW + ni * 16 + lane15;
    if (WHICH == 0)
      bv[ni] = (col < 1344) ? bias[col] : 0.f;
    else
      bv[ni] = bias[col];
  }

  int h = 0, ch0 = 0;
  if (mode == 1) {
    h = colW / 192;
    ch0 = colW % 192;
  } else if (mode == 2) {
    int jb = colW & 255;
    h = colW >> 8;
    ch0 = (jb < 128) ? (192 + jb) : (256 + jb);
  }
  const bool ropeTile = (mode == 1) && (ch0 == 128);

  __syncthreads();   // all waves done with K-loop LDS before reuse
  float* lw = (float*)smem + wave * (16 * 68);
  const int hi = lane15 >> 2, l3 = lane15 & 3;

#pragma unroll
  for (int mi = 0; mi < 4; ++mi) {
    f32x4 v[4];
#pragma unroll
    for (int ni = 0; ni < 4; ++ni)
#pragma unroll
      for (int rg = 0; rg < 4; ++rg) v[ni][rg] = acc[mi][ni][rg] + bv[ni];

    if (ropeTile) {
      int rowB = mTile + wm + mi * 16 + quad * 4;
#pragma unroll
      for (int rg = 0; rg < 4; ++rg) {
        int ss = (rowB + rg) & 4095;
#pragma unroll
        for (int ni = 0; ni < 2; ++ni) {
          int i = ni * 16 + lane15;
          float cv = cosT[ss * 32 + i], sv = sinT[ss * 32 + i];
          float x1 = v[ni][rg], x2 = v[ni + 2][rg];
          v[ni][rg] = x1 * cv - x2 * sv;
          v[ni + 2][rg] = x2 * cv + x1 * sv;
        }
      }
    }

    if (mi) asm volatile("s_waitcnt lgkmcnt(0)" ::: "memory");
#pragma unroll
    for (int ni = 0; ni < 4; ++ni) {
      int su = (4 * ni + hi) ^ quad;   // XOR low bits by writer quad (=rr>>2)
#pragma unroll
      for (int rg = 0; rg < 4; ++rg)
        lw[68 * (quad * 4 + rg) + 4 * su + l3] = v[ni][rg];
    }
    asm volatile("s_waitcnt lgkmcnt(0)" ::: "memory");
#pragma unroll
    for (int j = 0; j < 4; ++j) {
      int rr = 4 * j + quad;
      int su = lane15 ^ j;             // un-swizzle: writer quad for row rr is j
      float4 o = *(const float4*)&lw[68 * rr + 4 * su];
      int row = mTile + wm + mi * 16 + rr;
      if (mode == 0) {
        if (colW + 4 * lane15 < 1344)
          *(float4*)(C0 + (size_t)row * 1344 + colW + 4 * lane15) = o;
      } else {
        int bb = row >> 12, ss = row & 4095;
        size_t ob =
            ((size_t)((bb * 16 + h) * 4096 + ss)) * 512 + ch0 + 4 * lane15;
        *(float4*)(out + ob) = o;
      }
    }
  }
}

// ---------- LayerNorms + k_rot broadcast (vectorized, single reduction) ----------
// Row layout (1344 f32 = 336 float4): f4[0..191]=q_c, f4[192..319]=kv_c,
// f4[320..335]=k_rope. Thread t<256 loads f4[t]; t<80 also loads f4[256+t].

__global__ __launch_bounds__(256) void ln_rot(
    const float* __restrict__ qkvc, const float* __restrict__ g_q,
    const float* __restrict__ b_q, const float* __restrict__ g_kv,
    const float* __restrict__ b_kv, u16* __restrict__ q_ln,
    u16* __restrict__ kv_ln, const float* __restrict__ cosT,
    const float* __restrict__ sinT, float* __restrict__ out) {
  __shared__ float red[4][4];
  __shared__ __align__(16) float rot[64];
  const int tid = threadIdx.x;
  const int t = blockIdx.x;
  const int bb = t >> 12, ss = t & 4095;
  const float4* p4 = (const float4*)(qkvc + (size_t)t * 1344);

  float4 a = p4[tid];
  float4 b = make_float4(0.f, 0.f, 0.f, 0.f);
  if (tid < 80) b = p4[256 + tid];

  float sa = a.x + a.y + a.z + a.w;
  float sqa = a.x * a.x + a.y * a.y + a.z * a.z + a.w * a.w;
  float qs = 0.f, qq = 0.f, ks = 0.f, kq = 0.f;
  if (tid < 192) { qs = sa; qq = sqa; } else { ks = sa; kq = sqa; }
  if (tid < 64) {   // f4[256+tid] in kv range (256..319)
    ks += b.x + b.y + b.z + b.w;
    kq += b.x * b.x + b.y * b.y + b.z * b.z + b.w * b.w;
  }
#pragma unroll
  for (int off = 32; off > 0; off >>= 1) {
    qs += __shfl_down(qs, off, 64);
    qq += __shfl_down(qq, off, 64);
    ks += __shfl_down(ks, off, 64);
    kq += __shfl_down(kq, off, 64);
  }
  const int lane = tid & 63, wave = tid >> 6;
  if (lane == 0) {
    red[wave][0] = qs; red[wave][1] = qq;
    red[wave][2] = ks; red[wave][3] = kq;
  }
  __syncthreads();
  qs = red[0][0] + red[1][0] + red[2][0] + red[3][0];
  qq = red[0][1] + red[1][1] + red[2][1] + red[3][1];
  ks = red[0][2] + red[1][2] + red[2][2] + red[3][2];
  kq = red[0][3] + red[1][3] + red[2][3] + red[3][3];
  const float muq = qs * (1.f / 768.f);
  const float invq = rsqrtf(qq * (1.f / 768.f) - muq * muq + 1e-5f);
  const float muk = ks * (1.f / 512.f);
  const float invk = rsqrtf(kq * (1.f / 512.f) - muk * muk + 1e-5f);

  if (tid < 192) {
    float4 g = ((const float4*)g_q)[tid];
    float4 be = ((const float4*)b_q)[tid];
    float4 o = make_float4((a.x - muq) * invq * g.x + be.x,
                           (a.y - muq) * invq * g.y + be.y,
                           (a.z - muq) * invq * g.z + be.z,
                           (a.w - muq) * invq * g.w + be.w);
    ((ushort4*)(q_ln + (size_t)t * 768))[tid] = f2bf4(o);
  } else {
    int j = tid - 192;   // kv f4 col 0..63
    float4 g = ((const float4*)g_kv)[j];
    float4 be = ((const float4*)b_kv)[j];
    float4 o = make_float4((a.x - muk) * invk * g.x + be.x,
                           (a.y - muk) * invk * g.y + be.y,
                           (a.z - muk) * invk * g.z + be.z,
                           (a.w - muk) * invk * g.w + be.w);
    ((ushort4*)(kv_ln + (size_t)t * 512))[j] = f2bf4(o);
  }
  if (tid < 64) {
    int j = 64 + tid;    // kv f4 col 64..127
    float4 g = ((const float4*)g_kv)[j];
    float4 be = ((const float4*)b_kv)[j];
    float4 o = make_float4((b.x - muk) * invk * g.x + be.x,
                           (b.y - muk) * invk * g.y + be.y,
                           (b.z - muk) * invk * g.z + be.z,
                           (b.w - muk) * invk * g.w + be.w);
    ((ushort4*)(kv_ln + (size_t)t * 512))[j] = f2bf4(o);
  }
  // k_rot (64 ch), broadcast to 16 heads (out ch 320..383)
  if (tid < 32) {
    const float* p = qkvc + (size_t)t * 1344;
    float k1 = p[1280 + tid], k2 = p[1312 + tid];
    float cv = cosT[ss * 32 + tid], sv = sinT[ss * 32 + tid];
    rot[tid] = k1 * cv - k2 * sv;
    rot[tid + 32] = k2 * cv + k1 * sv;
  }
  __syncthreads();
  {
    int hh = tid >> 4, c4 = tid & 15;
    float4 o = ((const float4*)rot)[c4];
    *(float4*)(out + ((size_t)((bb * 16 + hh) * 4096 + ss)) * 512 + 320 +
               4 * c4) = o;
  }
}

// ---------- launch ----------

extern "C" void kernel_launch(void* const* d_in, const int* in_sizes, int n_in,
                              void* d_out, int out_size, void* d_ws,
                              size_t ws_size, hipStream_t stream) {
  const float* hidden = (const float*)d_in[0];
  const float* w_qa = (const float*)d_in[1];
  const float* b_qa = (const float*)d_in[2];
  const float* g_qa_ln = (const float*)d_in[3];
  const float* b_qa_ln = (const float*)d_in[4];
  const float* w_qb = (const float*)d_in[5];
  const float* b_qb = (const float*)d_in[6];
  const float* w_kva = (const float*)d_in[7];
  const float* b_kva = (const float*)d_in[8];
  const float* g_kva_ln = (const float*)d_in[9];
  const float* b_kva_ln = (const float*)d_in[10];
  const float* w_kvb = (const float*)d_in[11];
  const float* b_kvb = (const float*)d_in[12];
  float* out = (float*)d_out;

  char* ws = (char*)d_ws;
  u16* hid_bf = (u16*)ws;   ws += (size_t)16777216 * 2;
  u16* wab_bf = (u16*)ws;   ws += (size_t)1344 * 2048 * 2;
  u16* wqb_bf = (u16*)ws;   ws += (size_t)2359296 * 2;
  u16* wkvb_bf = (u16*)ws;  ws += (size_t)2097152 * 2;
  float* qkvc = (float*)ws; ws += (size_t)8192 * 1344 * 4;
  u16* q_ln = (u16*)ws;     ws += (size_t)6291456 * 2;
  u16* kv_ln = (u16*)ws;    ws += (size_t)4194304 * 2;
  float* cosT = (float*)ws; ws += (size_t)131072 * 4;
  float* sinT = (float*)ws; ws += (size_t)131072 * 4;
  float* bias_ab = (float*)ws; ws += (size_t)2048 * 4;

  prep<<<dim3(1024), dim3(256), 0, stream>>>(
      hidden, w_qa, w_kva, w_qb, w_kvb, b_qa, b_kva, hid_bf, wab_bf, wqb_bf,
      wkvb_bf, bias_ab, cosT, sinT);
  // merged A-GEMM: qkvc = hidden @ [w_qa;w_kva]^T + bias  (8192 x 1344, K=2048)
  gemm_k<0><<<dim3(64, 11), dim3(256), 0, stream>>>(
      hid_bf, wab_bf, bias_ab, qkvc, nullptr, nullptr, nullptr, nullptr,
      nullptr, nullptr, nullptr, cosT, sinT);
  ln_rot<<<dim3(8192), dim3(256), 0, stream>>>(qkvc, g_qa_ln, b_qa_ln,
                                               g_kva_ln, b_kva_ln, q_ln, kv_ln,
                                               cosT, sinT, out);
  // merged B-GEMMs: y<24 -> q (N=3072,K=768, RoPE fused); y>=24 -> kv (N=4096,K=512)
  gemm_k<1><<<dim3(64, 56), dim3(256), 0, stream>>>(
      nullptr, nullptr, nullptr, nullptr, q_ln, wqb_bf, b_qb, kv_ln, wkvb_bf,
      b_kvb, out, cosT, sinT);
}